// Round 3
// baseline (246.662 us; speedup 1.0000x reference)
//
#include <hip/hip_runtime.h>
#include <hip/hip_bf16.h>
#include <stdint.h>
#include <math.h>

#define EPS_CELL 1e-6f
#define LN_EPS   1e-5f

typedef short short8 __attribute__((ext_vector_type(8)));
typedef float f32x4 __attribute__((ext_vector_type(4)));
typedef unsigned short ushort;

__device__ __forceinline__ ushort f2bf(float f) {
    union { float f; uint32_t u; } v; v.f = f;
    uint32_t r = v.u + 0x7FFFu + ((v.u >> 16) & 1u);  // round-to-nearest-even
    return (ushort)(r >> 16);
}
__device__ __forceinline__ float bfbits2f(uint32_t hi16_in_place) {
    union { uint32_t u; float f; } v; v.u = hi16_in_place;
    return v.f;
}

// ---------------------------------------------------------------- cast f32->bf16
__global__ __launch_bounds__(256) void cast_f32_bf16(const float* __restrict__ in,
                                                     ushort* __restrict__ out,
                                                     int n) {
    int i = (blockIdx.x * 256 + threadIdx.x) * 8;
    if (i >= n) return;
    const float4* p = (const float4*)(in + i);
    float4 a = p[0], b = p[1];
    uint4 r;
    r.x = (uint32_t)f2bf(a.x) | ((uint32_t)f2bf(a.y) << 16);
    r.y = (uint32_t)f2bf(a.z) | ((uint32_t)f2bf(a.w) << 16);
    r.z = (uint32_t)f2bf(b.x) | ((uint32_t)f2bf(b.y) << 16);
    r.w = (uint32_t)f2bf(b.z) | ((uint32_t)f2bf(b.w) << 16);
    *(uint4*)(out + i) = r;
}

// ================================================================ 256x256 8-phase GEMM
// C[M,GN] = A[M,K] * B[GN,K]^T + bias, bf16 in/out.
// 8 waves (2M x 4N), BK=64, double-buffered 128 KiB LDS, T1+T2+T3+T4+T5.
// Staging pipeline: each buffer's 8 loads issued 3-4 phases before their
// counted vmcnt(4) wait (buf0-next: issue P4/P5, wait P8; buf1-next: issue
// P8/P1', wait P4').
#define BAR()        __builtin_amdgcn_s_barrier()
#define SPRIO(x)     __builtin_amdgcn_s_setprio(x)
#define WAIT_LGKM0() do { asm volatile("s_waitcnt lgkmcnt(0)" ::: "memory"); \
                          __builtin_amdgcn_sched_barrier(0); } while (0)
#define WAIT_VM4()   do { asm volatile("s_waitcnt vmcnt(4)" ::: "memory"); \
                          __builtin_amdgcn_sched_barrier(0); } while (0)
#define WAIT_VM0()   do { asm volatile("s_waitcnt vmcnt(0)" ::: "memory"); \
                          __builtin_amdgcn_sched_barrier(0); } while (0)

template<int K>
__global__ __launch_bounds__(512, 2) void gemm256_8ph(
        const ushort* __restrict__ Ag,   // [M, K]
        const ushort* __restrict__ Bg,   // [GN, K]
        const float*  __restrict__ bias, // [GN]
        ushort* __restrict__ C,          // [M, GN]
        int M, int GN) {
    constexpr int NT = K / 64;           // K-tiles
    constexpr int NP = NT / 2;           // pair iterations

    __shared__ ushort lds[65536];        // 128 KiB: buf0{A,B} buf1{A,B}, 16384 shorts each

    const int t    = threadIdx.x;        // 0..511
    const int lane = t & 63;
    const int w    = t >> 6;             // 0..7
    const int wr   = w >> 2;             // 0..1 (M half)
    const int wc   = w & 3;              // 0..3 (N quarter)
    const int ln   = lane & 15;
    const int hi   = lane >> 4;          // 0..3
    const int sx   = ln & 7;             // read-side XOR key (row&7)

    // XCD-aware bijective swizzle (gridDim.x = 512, %8==0)
    const int bid = blockIdx.x;
    const int wg  = (bid & 7) * 64 + (bid >> 3);
    const int n0  = (wg & 15) * 256;     // GN/256 = 16
    const int m0  = (wg >> 4) * 256;

    // staging: thread t stages 16B; dst is LINEAR (global_load_lds constraint);
    // the SOURCE column is pre-swizzled so that swizzled reads see linear data.
    const int trow = t >> 3;                          // 0..63 within a 64-row issue
    const int scol = (((t & 7) ^ (trow & 7)) * 8);    // shorts

#define STG_A(buf, j, kb) __builtin_amdgcn_global_load_lds( \
    (const __attribute__((address_space(1))) void*)(Ag + (size_t)(m0 + (j)*64 + trow) * K + (kb) + scol), \
    (__attribute__((address_space(3))) void*)(lds + (buf)*32768 + (j)*4096 + t*8), 16, 0, 0)
#define STG_B(buf, j, kb) __builtin_amdgcn_global_load_lds( \
    (const __attribute__((address_space(1))) void*)(Bg + (size_t)(n0 + (j)*64 + trow) * K + (kb) + scol), \
    (__attribute__((address_space(3))) void*)(lds + (buf)*32768 + 16384 + (j)*4096 + t*8), 16, 0, 0)

    // swizzled read offsets (shorts): row*64 + ((kk*4+hi)^(row&7))*8, row&7 == ln&7
    const int ca0  = ((0 + hi) ^ sx) * 8;             // kk = 0
    const int ca1  = ((4 + hi) ^ sx) * 8;             // kk = 1
    const int arow = (wr * 128 + ln) * 64;            // + m*1024
    const int brow = (wc * 64 + ln) * 64;             // + n*1024 (+16384 matrix base)

    short8 af[2][4], bf0[2][2], bf1[2][2];
    f32x4  acc[8][4] = {};

#define LD_A(buf, mbase) do { _Pragma("unroll") for (int m = 0; m < 4; ++m) { \
    af[0][m] = *(const short8*)&lds[(buf)*32768 + arow + ((mbase)+m)*1024 + ca0]; \
    af[1][m] = *(const short8*)&lds[(buf)*32768 + arow + ((mbase)+m)*1024 + ca1]; } } while (0)
#define LD_B(dst, buf, nbase) do { _Pragma("unroll") for (int n = 0; n < 2; ++n) { \
    dst[0][n] = *(const short8*)&lds[(buf)*32768 + 16384 + brow + ((nbase)+n)*1024 + ca0]; \
    dst[1][n] = *(const short8*)&lds[(buf)*32768 + 16384 + brow + ((nbase)+n)*1024 + ca1]; } } while (0)
#define MMQ(mb, nb, B_) do { _Pragma("unroll") for (int kk = 0; kk < 2; ++kk) \
    _Pragma("unroll") for (int m = 0; m < 4; ++m) \
    _Pragma("unroll") for (int n = 0; n < 2; ++n) \
        acc[(mb)+m][(nb)+n] = __builtin_amdgcn_mfma_f32_16x16x32_bf16( \
            af[kk][m], B_[kk][n], acc[(mb)+m][(nb)+n], 0, 0, 0); } while (0)

    // ---- prologue: tile0 -> buf0 (8 issues), tile1 B0..B3 -> buf1 (4 issues)
    STG_B(0,0,0); STG_B(0,1,0); STG_B(0,2,0); STG_B(0,3,0);
    STG_A(0,0,0); STG_A(0,1,0); STG_A(0,2,0); STG_A(0,3,0);
    STG_B(1,0,64); STG_B(1,1,64); STG_B(1,2,64); STG_B(1,3,64);
    WAIT_VM4(); BAR();   // drains buf0's 8; buf1 B x4 remain in flight

    // ---- main loop: iter p computes tiles 2p (buf0) and 2p+1 (buf1)
    for (int p = 0; p < NP; ++p) {
        const int k1 = (2*p + 1) * 64;                              // buf1 tile (this iter)
        const int t2 = (2*p + 2 < NT) ? (2*p + 2) : (2*p);          // next buf0 tile (L2-hot on wrap)
        const int t3 = (2*p + 3 < NT) ? (2*p + 3) : (2*p + 1);      // next buf1 tile
        const int k2 = t2 * 64, k3 = t3 * 64;

        // P1: 12 ds_read (buf0), finish staging buf1 (A x4)
        LD_A(0, 0); LD_B(bf0, 0, 0);
        STG_A(1,0,k1); STG_A(1,1,k1); STG_A(1,2,k1); STG_A(1,3,k1);
        BAR(); WAIT_LGKM0();
        SPRIO(1); MMQ(0,0,bf0); SPRIO(0); BAR();
        // P2: 4 ds_read
        LD_B(bf1, 0, 2);
        BAR(); WAIT_LGKM0();
        SPRIO(1); MMQ(0,2,bf1); SPRIO(0); BAR();
        // P3: 8 ds_read (last buf0 reads)
        LD_A(0, 4);
        BAR(); WAIT_LGKM0();
        SPRIO(1); MMQ(4,0,bf0); SPRIO(0); BAR();
        // P4: stage next buf0 B x4; counted wait -> buf1 fully landed
        STG_B(0,0,k2); STG_B(0,1,k2); STG_B(0,2,k2); STG_B(0,3,k2);
        BAR();
        SPRIO(1); MMQ(4,2,bf1); SPRIO(0);
        WAIT_VM4(); BAR();
        // P5: 12 ds_read (buf1), stage next buf0 A x4
        LD_A(1, 0); LD_B(bf0, 1, 0);
        STG_A(0,0,k2); STG_A(0,1,k2); STG_A(0,2,k2); STG_A(0,3,k2);
        BAR(); WAIT_LGKM0();
        SPRIO(1); MMQ(0,0,bf0); SPRIO(0); BAR();
        // P6: 4 ds_read
        LD_B(bf1, 1, 2);
        BAR(); WAIT_LGKM0();
        SPRIO(1); MMQ(0,2,bf1); SPRIO(0); BAR();
        // P7: 8 ds_read (last buf1 reads)
        LD_A(1, 4);
        BAR(); WAIT_LGKM0();
        SPRIO(1); MMQ(4,0,bf0); SPRIO(0); BAR();
        // P8: stage next buf1 B x4; counted wait -> next buf0 fully landed
        STG_B(1,0,k3); STG_B(1,1,k3); STG_B(1,2,k3); STG_B(1,3,k3);
        BAR();
        SPRIO(1); MMQ(4,2,bf1); SPRIO(0);
        WAIT_VM4(); BAR();
    }

    // ---- epilogue: stage C-tile in LDS (bf16, swizzled), then coalesced stores.
    WAIT_VM0();          // drain leftover staging loads still landing in lds
    BAR();
#pragma unroll
    for (int n = 0; n < 4; ++n) {
        int cl   = wc * 64 + n * 16 + ln;          // local col 0..255
        float bv = bias[n0 + cl];
#pragma unroll
        for (int m = 0; m < 8; ++m) {
#pragma unroll
            for (int r = 0; r < 4; ++r) {
                int row = wr * 128 + m * 16 + hi * 4 + r;
                int sc  = (cl & 7) + ((((cl >> 3) ^ (row & 7))) << 3);
                lds[row * 256 + sc] = f2bf(acc[m][n][r] + bv);
            }
        }
    }
    BAR();
    {
        const int rr = t >> 5;            // 0..15
        const int oc = (t & 31) * 8;      // short offset within row, 8-aligned
#pragma unroll
        for (int i = 0; i < 16; ++i) {
            int row = i * 16 + rr;
            int sc  = (((oc >> 3) ^ (row & 7)) << 3);
            uint4 vv = *(const uint4*)&lds[row * 256 + sc];
            *(uint4*)(C + (size_t)(m0 + row) * GN + n0 + oc) = vv;
        }
    }
#undef STG_A
#undef STG_B
#undef LD_A
#undef LD_B
#undef MMQ
}

// ---------------------------------------------------------------- block reduce (256 thr = 4 waves)
template<int NV>
__device__ __forceinline__ void block_reduce_sum(float* v, float* sred) {
    const int lane = threadIdx.x & 63;
    const int w    = threadIdx.x >> 6;
#pragma unroll
    for (int i = 0; i < NV; ++i) {
        float s = v[i];
#pragma unroll
        for (int o = 32; o > 0; o >>= 1) s += __shfl_down(s, o, 64);
        if (lane == 0) sred[i * 4 + w] = s;
    }
    __syncthreads();
#pragma unroll
    for (int i = 0; i < NV; ++i)
        v[i] = sred[i * 4 + 0] + sred[i * 4 + 1] + sred[i * 4 + 2] + sred[i * 4 + 3];
    __syncthreads();
}

// ---------------------------------------------------------------- fused row-wise cell
__global__ __launch_bounds__(256) void fused_cell(
        const ushort* __restrict__ U, const ushort* __restrict__ V,
        const float* __restrict__ c_prev,
        const float* __restrict__ g_in, const float* __restrict__ b_in,
        const float* __restrict__ g_hu, const float* __restrict__ b_hu,
        const float* __restrict__ g_c,  const float* __restrict__ b_c,
        const float* __restrict__ g_h,  const float* __restrict__ b_h,
        float* __restrict__ out_h, float* __restrict__ out_c) {
    __shared__ __align__(16) float sg[4096];
    __shared__ float sred[16];
    const int r = blockIdx.x;
    const int t = threadIdx.x;
    const size_t rowG = (size_t)r * 4096;
    const size_t rowH = (size_t)r * 1024;

    float uf[16], vf[16];
    {
        const uint4* pu = (const uint4*)(U + rowG + (size_t)t * 16);
        const uint4* pv = (const uint4*)(V + rowG + (size_t)t * 16);
        uint4 u0 = pu[0], u1 = pu[1], v0 = pv[0], v1 = pv[1];
        uint32_t uw[8] = {u0.x, u0.y, u0.z, u0.w, u1.x, u1.y, u1.z, u1.w};
        uint32_t vw[8] = {v0.x, v0.y, v0.z, v0.w, v1.x, v1.y, v1.z, v1.w};
#pragma unroll
        for (int j = 0; j < 8; ++j) {
            uf[2 * j]     = bfbits2f(uw[j] << 16);
            uf[2 * j + 1] = bfbits2f(uw[j] & 0xFFFF0000u);
            vf[2 * j]     = bfbits2f(vw[j] << 16);
            vf[2 * j + 1] = bfbits2f(vw[j] & 0xFFFF0000u);
        }
    }
    float red[4] = {0.f, 0.f, 0.f, 0.f};
#pragma unroll
    for (int j = 0; j < 16; ++j) {
        red[0] += uf[j]; red[1] += uf[j] * uf[j];
        red[2] += vf[j]; red[3] += vf[j] * vf[j];
    }
    block_reduce_sum<4>(red, sred);
    const float inv4096 = 1.f / 4096.f;
    float mu_u = red[0] * inv4096, mu_v = red[2] * inv4096;
    float rs_u = rsqrtf(red[1] * inv4096 - mu_u * mu_u + LN_EPS);
    float rs_v = rsqrtf(red[3] * inv4096 - mu_v * mu_v + LN_EPS);

#pragma unroll
    for (int j = 0; j < 16; ++j) {
        int idx = t * 16 + j;
        float zu = (uf[j] - mu_u) * rs_u;
        float zv = (vf[j] - mu_v) * rs_v;
        sg[idx] = zu * g_in[idx] + b_in[idx] + zv * g_hu[idx] + b_hu[idx];
    }
    __syncthreads();

    const float4* sg4 = (const float4*)sg;
    float4 gi4 = sg4[0 * 256 + t];
    float4 gf4 = sg4[1 * 256 + t];
    float4 gg4 = sg4[2 * 256 + t];
    float4 go4 = sg4[3 * 256 + t];
    float gi[4] = {gi4.x, gi4.y, gi4.z, gi4.w};
    float gf[4] = {gf4.x, gf4.y, gf4.z, gf4.w};
    float gg[4] = {gg4.x, gg4.y, gg4.z, gg4.w};
    float go[4] = {go4.x, go4.y, go4.z, go4.w};

    red[0] = gi[0] + gi[1] + gi[2] + gi[3];
    red[1] = gf[0] + gf[1] + gf[2] + gf[3];
    block_reduce_sum<2>(red, sred);
    const float inv1024 = 1.f / 1024.f;
    float mi = red[0] * inv1024, mf = red[1] * inv1024;

    float ei[4], ef[4];
#pragma unroll
    for (int q = 0; q < 4; ++q) {
        ei[q] = expf(fminf(fmaxf(gi[q] - mi, -5.f), 5.f));
        ef[q] = expf(fminf(fmaxf(gf[q] - mf, -5.f), 5.f));
    }
    red[0] = ei[0] + ei[1] + ei[2] + ei[3];
    red[1] = ef[0] + ef[1] + ef[2] + ef[3];
    block_reduce_sum<2>(red, sred);
    float inv_si = 1.f / (red[0] + EPS_CELL);
    float inv_sf = 1.f / (red[1] + EPS_CELL);

    const float4* cp4p = (const float4*)(c_prev + rowH);
    float4 cp4 = cp4p[t];
    float cprev[4] = {cp4.x, cp4.y, cp4.z, cp4.w};

    float cpv[4];
#pragma unroll
    for (int q = 0; q < 4; ++q) {
        float in_ = ei[q] * inv_si;
        float fn_ = ef[q] * inv_sf;
        float den = 1.f / (in_ + fn_ + EPS_CELL);
        float i2 = in_ * den, f2 = fn_ * den;
        cpv[q] = f2 * cprev[q] + i2 * tanhf(gg[q]);
    }
    red[0] = cpv[0] + cpv[1] + cpv[2] + cpv[3];
    red[1] = cpv[0] * cpv[0] + cpv[1] * cpv[1] + cpv[2] * cpv[2] + cpv[3] * cpv[3];
    block_reduce_sum<2>(red, sred);
    float mu_c = red[0] * inv1024;
    float rs_c = rsqrtf(red[1] * inv1024 - mu_c * mu_c + LN_EPS);

    float cv[4], th[4];
#pragma unroll
    for (int q = 0; q < 4; ++q) {
        int j = t * 4 + q;
        cv[q] = (cpv[q] - mu_c) * rs_c * g_c[j] + b_c[j];
        th[q] = tanhf(cv[q]);
    }
    {
        float4 o; o.x = cv[0]; o.y = cv[1]; o.z = cv[2]; o.w = cv[3];
        *(float4*)(out_c + rowH + (size_t)t * 4) = o;
    }
    red[0] = th[0] + th[1] + th[2] + th[3];
    red[1] = th[0] * th[0] + th[1] * th[1] + th[2] * th[2] + th[3] * th[3];
    block_reduce_sum<2>(red, sred);
    float mu_t = red[0] * inv1024;
    float rs_t = rsqrtf(red[1] * inv1024 - mu_t * mu_t + LN_EPS);

    float hv[4];
#pragma unroll
    for (int q = 0; q < 4; ++q) {
        int j = t * 4 + q;
        float co = (th[q] - mu_t) * rs_t * g_h[j] + b_h[j];
        float so = 1.f / (1.f + expf(-go[q]));
        hv[q] = so * co;
    }
    {
        float4 o; o.x = hv[0]; o.y = hv[1]; o.z = hv[2]; o.w = hv[3];
        *(float4*)(out_h + rowH + (size_t)t * 4) = o;
    }
}

// ---------------------------------------------------------------- launch
extern "C" void kernel_launch(void* const* d_in, const int* in_sizes, int n_in,
                              void* d_out, int out_size, void* d_ws, size_t ws_size,
                              hipStream_t stream) {
    const float* x       = (const float*)d_in[0];
    const float* h_prev  = (const float*)d_in[1];
    const float* c_prev  = (const float*)d_in[2];
    const float* Wx      = (const float*)d_in[3];
    const float* bx      = (const float*)d_in[4];
    const float* Wh      = (const float*)d_in[5];
    const float* bh      = (const float*)d_in[6];
    const float* ln_in_g = (const float*)d_in[7];
    const float* ln_in_b = (const float*)d_in[8];
    const float* ln_hu_g = (const float*)d_in[9];
    const float* ln_hu_b = (const float*)d_in[10];
    const float* ln_c_g  = (const float*)d_in[11];
    const float* ln_c_b  = (const float*)d_in[12];
    const float* ln_h_g  = (const float*)d_in[13];
    const float* ln_h_b  = (const float*)d_in[14];

    const int B = 8192, Din = 512, H = 1024, G = 4096;

    ushort* xb  = (ushort*)d_ws;                  // B*Din
    ushort* hb  = xb  + (size_t)B * Din;          // B*H
    ushort* wxb = hb  + (size_t)B * H;            // G*Din
    ushort* whb = wxb + (size_t)G * Din;          // G*H
    ushort* U   = whb + (size_t)G * H;            // B*G
    ushort* V   = U   + (size_t)B * G;            // B*G

    cast_f32_bf16<<<(B * Din) / 2048, 256, 0, stream>>>(x, xb, B * Din);
    cast_f32_bf16<<<(B * H)   / 2048, 256, 0, stream>>>(h_prev, hb, B * H);
    cast_f32_bf16<<<(G * Din) / 2048, 256, 0, stream>>>(Wx, wxb, G * Din);
    cast_f32_bf16<<<(G * H)   / 2048, 256, 0, stream>>>(Wh, whb, G * H);

    // grid: (G/256) * (B/256) = 16 * 32 = 512 blocks, 512 threads
    gemm256_8ph<512> <<<dim3(512), 512, 0, stream>>>(xb, wxb, bx, U, B, G);
    gemm256_8ph<1024><<<dim3(512), 512, 0, stream>>>(hb, whb, bh, V, B, G);

    float* out_h = (float*)d_out;
    float* out_c = out_h + (size_t)B * H;
    fused_cell<<<B, 256, 0, stream>>>(U, V, c_prev,
                                      ln_in_g, ln_in_b, ln_hu_g, ln_hu_b,
                                      ln_c_g, ln_c_b, ln_h_g, ln_h_b,
                                      out_h, out_c);
}

// Round 4
// 224.065 us; speedup vs baseline: 1.1009x; 1.1009x over previous
//
#include <hip/hip_runtime.h>
#include <hip/hip_bf16.h>
#include <stdint.h>
#include <math.h>

#define EPS_CELL 1e-6f
#define LN_EPS   1e-5f

typedef short short8 __attribute__((ext_vector_type(8)));
typedef float f32x4 __attribute__((ext_vector_type(4)));
typedef unsigned short ushort;

__device__ __forceinline__ ushort f2bf(float f) {
    union { float f; uint32_t u; } v; v.f = f;
    uint32_t r = v.u + 0x7FFFu + ((v.u >> 16) & 1u);  // round-to-nearest-even
    return (ushort)(r >> 16);
}
__device__ __forceinline__ float bfbits2f(uint32_t hi16_in_place) {
    union { uint32_t u; float f; } v; v.u = hi16_in_place;
    return v.f;
}

// fast math: single-instruction HW transcendentals (v_exp_f32/v_rcp_f32/v_rsq_f32)
__device__ __forceinline__ float fexp(float x)  { return __builtin_amdgcn_exp2f(x * 1.4426950408889634f); }
__device__ __forceinline__ float frcp(float x)  { return __builtin_amdgcn_rcpf(x); }
__device__ __forceinline__ float frsq(float x)  { return __builtin_amdgcn_rsqf(x); }
__device__ __forceinline__ float ftanh(float x) {
    float xc = fminf(fmaxf(x, -15.f), 15.f);
    float t  = fexp(2.f * xc);                 // e^{2x}, <= e^30 ~ 1e13, no overflow
    return (t - 1.f) * frcp(t + 1.f);
}
__device__ __forceinline__ float fsigm(float x) { return frcp(1.f + fexp(-x)); }

// ---------------------------------------------------------------- cast f32->bf16
__global__ __launch_bounds__(256) void cast_f32_bf16(const float* __restrict__ in,
                                                     ushort* __restrict__ out,
                                                     int n) {
    int i = (blockIdx.x * 256 + threadIdx.x) * 8;
    if (i >= n) return;
    const float4* p = (const float4*)(in + i);
    float4 a = p[0], b = p[1];
    uint4 r;
    r.x = (uint32_t)f2bf(a.x) | ((uint32_t)f2bf(a.y) << 16);
    r.y = (uint32_t)f2bf(a.z) | ((uint32_t)f2bf(a.w) << 16);
    r.z = (uint32_t)f2bf(b.x) | ((uint32_t)f2bf(b.y) << 16);
    r.w = (uint32_t)f2bf(b.z) | ((uint32_t)f2bf(b.w) << 16);
    *(uint4*)(out + i) = r;
}

// ================================================================ 256x256 8-phase GEMM
// (unchanged from round 3)
#define BAR()        __builtin_amdgcn_s_barrier()
#define SPRIO(x)     __builtin_amdgcn_s_setprio(x)
#define WAIT_LGKM0() do { asm volatile("s_waitcnt lgkmcnt(0)" ::: "memory"); \
                          __builtin_amdgcn_sched_barrier(0); } while (0)
#define WAIT_VM4()   do { asm volatile("s_waitcnt vmcnt(4)" ::: "memory"); \
                          __builtin_amdgcn_sched_barrier(0); } while (0)
#define WAIT_VM0()   do { asm volatile("s_waitcnt vmcnt(0)" ::: "memory"); \
                          __builtin_amdgcn_sched_barrier(0); } while (0)

template<int K>
__global__ __launch_bounds__(512, 2) void gemm256_8ph(
        const ushort* __restrict__ Ag,   // [M, K]
        const ushort* __restrict__ Bg,   // [GN, K]
        const float*  __restrict__ bias, // [GN]
        ushort* __restrict__ C,          // [M, GN]
        int M, int GN) {
    constexpr int NT = K / 64;           // K-tiles
    constexpr int NP = NT / 2;           // pair iterations

    __shared__ ushort lds[65536];        // 128 KiB: buf0{A,B} buf1{A,B}

    const int t    = threadIdx.x;        // 0..511
    const int lane = t & 63;
    const int w    = t >> 6;             // 0..7
    const int wr   = w >> 2;             // 0..1 (M half)
    const int wc   = w & 3;              // 0..3 (N quarter)
    const int ln   = lane & 15;
    const int hi   = lane >> 4;          // 0..3
    const int sx   = ln & 7;             // read-side XOR key (row&7)

    const int bid = blockIdx.x;
    const int wg  = (bid & 7) * 64 + (bid >> 3);
    const int n0  = (wg & 15) * 256;     // GN/256 = 16
    const int m0  = (wg >> 4) * 256;

    const int trow = t >> 3;
    const int scol = (((t & 7) ^ (trow & 7)) * 8);

#define STG_A(buf, j, kb) __builtin_amdgcn_global_load_lds( \
    (const __attribute__((address_space(1))) void*)(Ag + (size_t)(m0 + (j)*64 + trow) * K + (kb) + scol), \
    (__attribute__((address_space(3))) void*)(lds + (buf)*32768 + (j)*4096 + t*8), 16, 0, 0)
#define STG_B(buf, j, kb) __builtin_amdgcn_global_load_lds( \
    (const __attribute__((address_space(1))) void*)(Bg + (size_t)(n0 + (j)*64 + trow) * K + (kb) + scol), \
    (__attribute__((address_space(3))) void*)(lds + (buf)*32768 + 16384 + (j)*4096 + t*8), 16, 0, 0)

    const int ca0  = ((0 + hi) ^ sx) * 8;
    const int ca1  = ((4 + hi) ^ sx) * 8;
    const int arow = (wr * 128 + ln) * 64;
    const int brow = (wc * 64 + ln) * 64;

    short8 af[2][4], bf0[2][2], bf1[2][2];
    f32x4  acc[8][4] = {};

#define LD_A(buf, mbase) do { _Pragma("unroll") for (int m = 0; m < 4; ++m) { \
    af[0][m] = *(const short8*)&lds[(buf)*32768 + arow + ((mbase)+m)*1024 + ca0]; \
    af[1][m] = *(const short8*)&lds[(buf)*32768 + arow + ((mbase)+m)*1024 + ca1]; } } while (0)
#define LD_B(dst, buf, nbase) do { _Pragma("unroll") for (int n = 0; n < 2; ++n) { \
    dst[0][n] = *(const short8*)&lds[(buf)*32768 + 16384 + brow + ((nbase)+n)*1024 + ca0]; \
    dst[1][n] = *(const short8*)&lds[(buf)*32768 + 16384 + brow + ((nbase)+n)*1024 + ca1]; } } while (0)
#define MMQ(mb, nb, B_) do { _Pragma("unroll") for (int kk = 0; kk < 2; ++kk) \
    _Pragma("unroll") for (int m = 0; m < 4; ++m) \
    _Pragma("unroll") for (int n = 0; n < 2; ++n) \
        acc[(mb)+m][(nb)+n] = __builtin_amdgcn_mfma_f32_16x16x32_bf16( \
            af[kk][m], B_[kk][n], acc[(mb)+m][(nb)+n], 0, 0, 0); } while (0)

    // ---- prologue
    STG_B(0,0,0); STG_B(0,1,0); STG_B(0,2,0); STG_B(0,3,0);
    STG_A(0,0,0); STG_A(0,1,0); STG_A(0,2,0); STG_A(0,3,0);
    STG_B(1,0,64); STG_B(1,1,64); STG_B(1,2,64); STG_B(1,3,64);
    WAIT_VM4(); BAR();

    for (int p = 0; p < NP; ++p) {
        const int k1 = (2*p + 1) * 64;
        const int t2 = (2*p + 2 < NT) ? (2*p + 2) : (2*p);
        const int t3 = (2*p + 3 < NT) ? (2*p + 3) : (2*p + 1);
        const int k2 = t2 * 64, k3 = t3 * 64;

        // P1
        LD_A(0, 0); LD_B(bf0, 0, 0);
        STG_A(1,0,k1); STG_A(1,1,k1); STG_A(1,2,k1); STG_A(1,3,k1);
        BAR(); WAIT_LGKM0();
        SPRIO(1); MMQ(0,0,bf0); SPRIO(0); BAR();
        // P2
        LD_B(bf1, 0, 2);
        BAR(); WAIT_LGKM0();
        SPRIO(1); MMQ(0,2,bf1); SPRIO(0); BAR();
        // P3
        LD_A(0, 4);
        BAR(); WAIT_LGKM0();
        SPRIO(1); MMQ(4,0,bf0); SPRIO(0); BAR();
        // P4
        STG_B(0,0,k2); STG_B(0,1,k2); STG_B(0,2,k2); STG_B(0,3,k2);
        BAR();
        SPRIO(1); MMQ(4,2,bf1); SPRIO(0);
        WAIT_VM4(); BAR();
        // P5
        LD_A(1, 0); LD_B(bf0, 1, 0);
        STG_A(0,0,k2); STG_A(0,1,k2); STG_A(0,2,k2); STG_A(0,3,k2);
        BAR(); WAIT_LGKM0();
        SPRIO(1); MMQ(0,0,bf0); SPRIO(0); BAR();
        // P6
        LD_B(bf1, 1, 2);
        BAR(); WAIT_LGKM0();
        SPRIO(1); MMQ(0,2,bf1); SPRIO(0); BAR();
        // P7
        LD_A(1, 4);
        BAR(); WAIT_LGKM0();
        SPRIO(1); MMQ(4,0,bf0); SPRIO(0); BAR();
        // P8
        STG_B(1,0,k3); STG_B(1,1,k3); STG_B(1,2,k3); STG_B(1,3,k3);
        BAR();
        SPRIO(1); MMQ(4,2,bf1); SPRIO(0);
        WAIT_VM4(); BAR();
    }

    // ---- epilogue: stage C-tile in LDS (bf16, swizzled), then coalesced stores.
    WAIT_VM0();
    BAR();
#pragma unroll
    for (int n = 0; n < 4; ++n) {
        int cl   = wc * 64 + n * 16 + ln;
        float bv = bias[n0 + cl];
#pragma unroll
        for (int m = 0; m < 8; ++m) {
#pragma unroll
            for (int r = 0; r < 4; ++r) {
                int row = wr * 128 + m * 16 + hi * 4 + r;
                int sc  = (cl & 7) + ((((cl >> 3) ^ (row & 7))) << 3);
                lds[row * 256 + sc] = f2bf(acc[m][n][r] + bv);
            }
        }
    }
    BAR();
    {
        const int rr = t >> 5;
        const int oc = (t & 31) * 8;
#pragma unroll
        for (int i = 0; i < 16; ++i) {
            int row = i * 16 + rr;
            int sc  = (((oc >> 3) ^ (row & 7)) << 3);
            uint4 vv = *(const uint4*)&lds[row * 256 + sc];
            *(uint4*)(C + (size_t)(m0 + row) * GN + n0 + oc) = vv;
        }
    }
#undef STG_A
#undef STG_B
#undef LD_A
#undef LD_B
#undef MMQ
}

// ---------------------------------------------------------------- block reduce (256 thr = 4 waves)
template<int NV>
__device__ __forceinline__ void block_reduce_sum(float* v, float* sred) {
    const int lane = threadIdx.x & 63;
    const int w    = threadIdx.x >> 6;
#pragma unroll
    for (int i = 0; i < NV; ++i) {
        float s = v[i];
#pragma unroll
        for (int o = 32; o > 0; o >>= 1) s += __shfl_down(s, o, 64);
        if (lane == 0) sred[i * 4 + w] = s;
    }
    __syncthreads();
#pragma unroll
    for (int i = 0; i < NV; ++i)
        v[i] = sred[i * 4 + 0] + sred[i * 4 + 1] + sred[i * 4 + 2] + sred[i * 4 + 3];
    __syncthreads();
}

// ---------------------------------------------------------------- fused row-wise cell
// one block (256 thr) per batch row. Thread t owns elements [t*4, t*4+4) of
// EACH gate quarter -> gates live entirely in registers, no LDS staging.
__global__ __launch_bounds__(256) void fused_cell(
        const ushort* __restrict__ U, const ushort* __restrict__ V,
        const float* __restrict__ c_prev,
        const float* __restrict__ g_in, const float* __restrict__ b_in,
        const float* __restrict__ g_hu, const float* __restrict__ b_hu,
        const float* __restrict__ g_c,  const float* __restrict__ b_c,
        const float* __restrict__ g_h,  const float* __restrict__ b_h,
        float* __restrict__ out_h, float* __restrict__ out_c) {
    __shared__ float sred[16];
    const int r = blockIdx.x;
    const int t = threadIdx.x;
    const size_t rowG = (size_t)r * 4096;
    const size_t rowH = (size_t)r * 1024;
    const int c0 = t * 4;                    // column base within each quarter

    // --- load u,v per gate quarter: 4 x 8B per matrix, coalesced
    float uq[4][4], vq[4][4];
#pragma unroll
    for (int q = 0; q < 4; ++q) {
        uint2 uu = *(const uint2*)(U + rowG + q * 1024 + c0);
        uint2 vv = *(const uint2*)(V + rowG + q * 1024 + c0);
        uq[q][0] = bfbits2f(uu.x << 16); uq[q][1] = bfbits2f(uu.x & 0xFFFF0000u);
        uq[q][2] = bfbits2f(uu.y << 16); uq[q][3] = bfbits2f(uu.y & 0xFFFF0000u);
        vq[q][0] = bfbits2f(vv.x << 16); vq[q][1] = bfbits2f(vv.x & 0xFFFF0000u);
        vq[q][2] = bfbits2f(vv.y << 16); vq[q][3] = bfbits2f(vv.y & 0xFFFF0000u);
    }

    float red[4] = {0.f, 0.f, 0.f, 0.f};
#pragma unroll
    for (int q = 0; q < 4; ++q)
#pragma unroll
        for (int j = 0; j < 4; ++j) {
            red[0] += uq[q][j]; red[1] += uq[q][j] * uq[q][j];
            red[2] += vq[q][j]; red[3] += vq[q][j] * vq[q][j];
        }
    block_reduce_sum<4>(red, sred);
    const float inv4096 = 1.f / 4096.f;
    float mu_u = red[0] * inv4096, mu_v = red[2] * inv4096;
    float rs_u = frsq(red[1] * inv4096 - mu_u * mu_u + LN_EPS);
    float rs_v = frsq(red[3] * inv4096 - mu_v * mu_v + LN_EPS);

    // --- gates = LN(u)*g1+b1 + LN(v)*g2+b2, in registers
    float gate[4][4];
#pragma unroll
    for (int q = 0; q < 4; ++q) {
        int idx = q * 1024 + c0;
        float4 gi_ = *(const float4*)(g_in + idx);
        float4 bi_ = *(const float4*)(b_in + idx);
        float4 gh_ = *(const float4*)(g_hu + idx);
        float4 bh_ = *(const float4*)(b_hu + idx);
        float gia[4] = {gi_.x, gi_.y, gi_.z, gi_.w};
        float bia[4] = {bi_.x, bi_.y, bi_.z, bi_.w};
        float gha[4] = {gh_.x, gh_.y, gh_.z, gh_.w};
        float bha[4] = {bh_.x, bh_.y, bh_.z, bh_.w};
#pragma unroll
        for (int j = 0; j < 4; ++j) {
            float zu = (uq[q][j] - mu_u) * rs_u;
            float zv = (vq[q][j] - mu_v) * rs_v;
            gate[q][j] = zu * gia[j] + bia[j] + zv * gha[j] + bha[j];
        }
    }

    // --- normalized exp gates (i = gate[0], f = gate[1])
    red[0] = gate[0][0] + gate[0][1] + gate[0][2] + gate[0][3];
    red[1] = gate[1][0] + gate[1][1] + gate[1][2] + gate[1][3];
    block_reduce_sum<2>(red, sred);
    const float inv1024 = 1.f / 1024.f;
    float mi = red[0] * inv1024, mf = red[1] * inv1024;

    float ei[4], ef[4];
#pragma unroll
    for (int q = 0; q < 4; ++q) {
        ei[q] = fexp(fminf(fmaxf(gate[0][q] - mi, -5.f), 5.f));
        ef[q] = fexp(fminf(fmaxf(gate[1][q] - mf, -5.f), 5.f));
    }
    red[0] = ei[0] + ei[1] + ei[2] + ei[3];
    red[1] = ef[0] + ef[1] + ef[2] + ef[3];
    block_reduce_sum<2>(red, sred);
    float inv_si = frcp(red[0] + EPS_CELL);
    float inv_sf = frcp(red[1] + EPS_CELL);

    float4 cp4 = *(const float4*)(c_prev + rowH + c0);
    float cprev[4] = {cp4.x, cp4.y, cp4.z, cp4.w};

    float cpv[4];
#pragma unroll
    for (int q = 0; q < 4; ++q) {
        float in_ = ei[q] * inv_si;
        float fn_ = ef[q] * inv_sf;
        float den = frcp(in_ + fn_ + EPS_CELL);
        float i2 = in_ * den, f2 = fn_ * den;
        cpv[q] = f2 * cprev[q] + i2 * ftanh(gate[2][q]);
    }
    red[0] = cpv[0] + cpv[1] + cpv[2] + cpv[3];
    red[1] = cpv[0] * cpv[0] + cpv[1] * cpv[1] + cpv[2] * cpv[2] + cpv[3] * cpv[3];
    block_reduce_sum<2>(red, sred);
    float mu_c = red[0] * inv1024;
    float rs_c = frsq(red[1] * inv1024 - mu_c * mu_c + LN_EPS);

    float cv[4], th[4];
    {
        float4 gc4 = *(const float4*)(g_c + c0);
        float4 bc4 = *(const float4*)(b_c + c0);
        float gca[4] = {gc4.x, gc4.y, gc4.z, gc4.w};
        float bca[4] = {bc4.x, bc4.y, bc4.z, bc4.w};
#pragma unroll
        for (int q = 0; q < 4; ++q) {
            cv[q] = (cpv[q] - mu_c) * rs_c * gca[q] + bca[q];
            th[q] = ftanh(cv[q]);
        }
    }
    {
        float4 o; o.x = cv[0]; o.y = cv[1]; o.z = cv[2]; o.w = cv[3];
        *(float4*)(out_c + rowH + c0) = o;
    }
    red[0] = th[0] + th[1] + th[2] + th[3];
    red[1] = th[0] * th[0] + th[1] * th[1] + th[2] * th[2] + th[3] * th[3];
    block_reduce_sum<2>(red, sred);
    float mu_t = red[0] * inv1024;
    float rs_t = frsq(red[1] * inv1024 - mu_t * mu_t + LN_EPS);

    float hv[4];
    {
        float4 gh4 = *(const float4*)(g_h + c0);
        float4 bh4 = *(const float4*)(b_h + c0);
        float gha[4] = {gh4.x, gh4.y, gh4.z, gh4.w};
        float bha[4] = {bh4.x, bh4.y, bh4.z, bh4.w};
#pragma unroll
        for (int q = 0; q < 4; ++q) {
            float co = (th[q] - mu_t) * rs_t * gha[q] + bha[q];
            float so = fsigm(gate[3][q]);
            hv[q] = so * co;
        }
    }
    {
        float4 o; o.x = hv[0]; o.y = hv[1]; o.z = hv[2]; o.w = hv[3];
        *(float4*)(out_h + rowH + c0) = o;
    }
}

// ---------------------------------------------------------------- launch
extern "C" void kernel_launch(void* const* d_in, const int* in_sizes, int n_in,
                              void* d_out, int out_size, void* d_ws, size_t ws_size,
                              hipStream_t stream) {
    const float* x       = (const float*)d_in[0];
    const float* h_prev  = (const float*)d_in[1];
    const float* c_prev  = (const float*)d_in[2];
    const float* Wx      = (const float*)d_in[3];
    const float* bx      = (const float*)d_in[4];
    const float* Wh      = (const float*)d_in[5];
    const float* bh      = (const float*)d_in[6];
    const float* ln_in_g = (const float*)d_in[7];
    const float* ln_in_b = (const float*)d_in[8];
    const float* ln_hu_g = (const float*)d_in[9];
    const float* ln_hu_b = (const float*)d_in[10];
    const float* ln_c_g  = (const float*)d_in[11];
    const float* ln_c_b  = (const float*)d_in[12];
    const float* ln_h_g  = (const float*)d_in[13];
    const float* ln_h_b  = (const float*)d_in[14];

    const int B = 8192, Din = 512, H = 1024, G = 4096;

    ushort* xb  = (ushort*)d_ws;                  // B*Din
    ushort* hb  = xb  + (size_t)B * Din;          // B*H
    ushort* wxb = hb  + (size_t)B * H;            // G*Din
    ushort* whb = wxb + (size_t)G * Din;          // G*H
    ushort* U   = whb + (size_t)G * H;            // B*G
    ushort* V   = U   + (size_t)B * G;            // B*G

    cast_f32_bf16<<<(B * Din) / 2048, 256, 0, stream>>>(x, xb, B * Din);
    cast_f32_bf16<<<(B * H)   / 2048, 256, 0, stream>>>(h_prev, hb, B * H);
    cast_f32_bf16<<<(G * Din) / 2048, 256, 0, stream>>>(Wx, wxb, G * Din);
    cast_f32_bf16<<<(G * H)   / 2048, 256, 0, stream>>>(Wh, whb, G * H);

    // grid: (G/256) * (B/256) = 16 * 32 = 512 blocks, 512 threads
    gemm256_8ph<512> <<<dim3(512), 512, 0, stream>>>(xb, wxb, bx, U, B, G);
    gemm256_8ph<1024><<<dim3(512), 512, 0, stream>>>(hb, whb, bh, V, B, G);

    float* out_h = (float*)d_out;
    float* out_c = out_h + (size_t)B * H;
    fused_cell<<<B, 256, 0, stream>>>(U, V, c_prev,
                                      ln_in_g, ln_in_b, ln_hu_g, ln_hu_b,
                                      ln_c_g, ln_c_b, ln_h_g, ln_h_b,
                                      out_h, out_c);
}